// Round 6
// baseline (888.780 us; speedup 1.0000x reference)
//
#include <hip/hip_runtime.h>

// Fused shifted-window cross-attention — head-per-wave MFMA structure.
// 2048 blocks x 384 threads (6 waves); wave w owns head w end-to-end.
// All per-head tensors live in registers; MFMA C-layout -> A/B-frag layout
// changes bounce through a WAVE-PRIVATE LDS slot (no barriers, lgkmcnt only).
// Slot reuse timeline per wave: Q -> K -> V^T -> P. Only the head-concat
// out-projection needs block sync: 2 barriers total (was 13).
// x/b rows + fp16 weights + bias/mask table read straight from global (L2-hot).
// LDS = 6*64*72 fp16 = 55.3KB (sO[64][200] aliases the pool) -> 2 blocks/CU.

#define IMG 256
#define SHIFTV 4
#define SCALE_F 0.17677669529663687f

typedef __attribute__((ext_vector_type(8))) _Float16 h8;
typedef __attribute__((ext_vector_type(4))) float f4;

#define MFMA(a, b, c) __builtin_amdgcn_mfma_f32_16x16x32_f16((a), (b), (c), 0, 0, 0)

__device__ __forceinline__ h8 cvt8(const float* __restrict__ p)
{
    const float4 f0 = *(const float4*)p;
    const float4 f1 = *(const float4*)(p + 4);
    h8 a;
    a[0] = (_Float16)f0.x; a[1] = (_Float16)f0.y;
    a[2] = (_Float16)f0.z; a[3] = (_Float16)f0.w;
    a[4] = (_Float16)f1.x; a[5] = (_Float16)f1.y;
    a[6] = (_Float16)f1.z; a[7] = (_Float16)f1.w;
    return a;
}

// ===== prep: weights fp32 -> fp16 (n-major rows), 4 x 192x192 =====
__global__ void prep_weights(const float* __restrict__ wqb,
                             const float* __restrict__ wqkv,
                             const float* __restrict__ wout,
                             _Float16* __restrict__ dst)
{
    const int i = blockIdx.x * 256 + threadIdx.x;        // 0..147455
    const int m = i / 36864, r = i - m * 36864;
    float v;
    if (m == 0)      v = wqb[r];                         // Wq  = w_qkv_b rows 0..191
    else if (m == 1) v = wqkv[36864 + r];                // Wk  = w_qkv rows 192..383
    else if (m == 2) v = wqkv[73728 + r];                // Wv  = w_qkv rows 384..575
    else             v = wout[r];                        // Wo
    dst[i] = (_Float16)v;
}

// ===== prep: bias+mask table [type][head][q][k] f32 (mask -> -1e30) =====
__global__ void prep_table(const float* __restrict__ rel, float* __restrict__ tab)
{
    const int i = blockIdx.x * 256 + threadIdx.x;        // 4*6*64*64 = 98304
    const int k = i & 63, q = (i >> 6) & 63;
    const int th = i >> 12;                              // ty*6 + h
    const int h = th % 6, ty = th / 6;
    const int pr = q >> 3, pc = q & 7, qr = k >> 3, qc = k & 7;
    const bool msk = ((ty & 1) && ((pr < 4) != (qr < 4))) ||
                     ((ty & 2) && ((pc < 4) != (qc < 4)));
    const float bias = rel[h * 225 + (pr - qr + 7) * 15 + (pc - qc + 7)];
    tab[i] = msk ? -1e30f : bias;
}

// ===== main fused kernel: head-per-wave =====
__global__ __launch_bounds__(384, 3)
void wmca_hpw(const float* __restrict__ x, const float* __restrict__ bten,
              const float* __restrict__ b_qkv, const float* __restrict__ b_qkv_b,
              const float* __restrict__ b_out,
              const _Float16* __restrict__ wh, const float* __restrict__ tab,
              float* __restrict__ out)
{
    __shared__ _Float16 sPool[6 * 64 * 72];   // per-wave bounce slots; later O-concat

    const int t = threadIdx.x;
    const int w = t >> 6;                      // wave id == head id
    const int l = t & 63, g = l >> 4, c16 = l & 15;

    const int wid = blockIdx.x;
    const int bi = wid >> 10, whi = (wid >> 5) & 31, wwi = wid & 31;
    const int ty = ((whi == 31) ? 1 : 0) | ((wwi == 31) ? 2 : 0);

    _Float16* bounce = sPool + w * (64 * 72);

    // per-lane global row bases for window tokens 16m + c16 (shift folded in)
    const float* xR[4]; const float* bR[4];
#pragma unroll
    for (int m = 0; m < 4; ++m) {
        const int tok = 16 * m + c16;
        const int ho = (whi * 8 + (tok >> 3) + SHIFTV) & 255;
        const int wo = (wwi * 8 + (tok & 7) + SHIFTV) & 255;
        const int base = ((bi * IMG + ho) * IMG + wo) * 192;
        xR[m] = x + base; bR[m] = bten + base;
    }

    const _Float16* Wq = wh;
    const _Float16* Wk = wh + 36864;
    const _Float16* Wv = wh + 2 * 36864;
    const _Float16* Wo = wh + 3 * 36864;

    // ---------------- Q = b @ Wq^T (+bias), scaled ----------------
    {
        f4 qacc[4][2];
#pragma unroll
        for (int n = 0; n < 2; ++n) {
            const float bb = b_qkv_b[w * 32 + 16 * n + c16];
#pragma unroll
            for (int m = 0; m < 4; ++m) qacc[m][n] = (f4){bb, bb, bb, bb};
        }
#pragma unroll
        for (int ks = 0; ks < 6; ++ks) {
            h8 wB0 = *(const h8*)(Wq + (w * 32 + c16) * 192 + 32 * ks + 8 * g);
            h8 wB1 = *(const h8*)(Wq + (w * 32 + 16 + c16) * 192 + 32 * ks + 8 * g);
#pragma unroll
            for (int m = 0; m < 4; ++m) {
                const h8 aB = cvt8(bR[m] + 32 * ks + 8 * g);
                qacc[m][0] = MFMA(aB, wB0, qacc[m][0]);
                qacc[m][1] = MFMA(aB, wB1, qacc[m][1]);
            }
        }
#pragma unroll
        for (int m = 0; m < 4; ++m)
#pragma unroll
            for (int n = 0; n < 2; ++n)
#pragma unroll
                for (int rg = 0; rg < 4; ++rg)
                    bounce[(16 * m + 4 * g + rg) * 72 + 16 * n + c16] =
                        (_Float16)(qacc[m][n][rg] * SCALE_F);
    }
    h8 qa[4];
#pragma unroll
    for (int m = 0; m < 4; ++m)
        qa[m] = *(const h8*)(bounce + (16 * m + c16) * 72 + 8 * g);

    // ---------------- K = x @ Wk^T (+bias) ----------------
    {
        f4 kacc[4][2];
#pragma unroll
        for (int n = 0; n < 2; ++n) {
            const float bb = b_qkv[192 + w * 32 + 16 * n + c16];
#pragma unroll
            for (int m = 0; m < 4; ++m) kacc[m][n] = (f4){bb, bb, bb, bb};
        }
#pragma unroll
        for (int ks = 0; ks < 6; ++ks) {
            h8 wB0 = *(const h8*)(Wk + (w * 32 + c16) * 192 + 32 * ks + 8 * g);
            h8 wB1 = *(const h8*)(Wk + (w * 32 + 16 + c16) * 192 + 32 * ks + 8 * g);
#pragma unroll
            for (int m = 0; m < 4; ++m) {
                const h8 aB = cvt8(xR[m] + 32 * ks + 8 * g);
                kacc[m][0] = MFMA(aB, wB0, kacc[m][0]);
                kacc[m][1] = MFMA(aB, wB1, kacc[m][1]);
            }
        }
#pragma unroll
        for (int m = 0; m < 4; ++m)
#pragma unroll
            for (int n = 0; n < 2; ++n)
#pragma unroll
                for (int rg = 0; rg < 4; ++rg)
                    bounce[(16 * m + 4 * g + rg) * 72 + 16 * n + c16] =
                        (_Float16)kacc[m][n][rg];
    }
    h8 kb[4];
#pragma unroll
    for (int n = 0; n < 4; ++n)
        kb[n] = *(const h8*)(bounce + (16 * n + c16) * 72 + 8 * g);

    // ---------------- V^T = Wv @ x^T (+bias): lands transposed ----------------
    {
        f4 vacc[2][4];
#pragma unroll
        for (int mv = 0; mv < 2; ++mv) {
            const float4 bv = *(const float4*)(b_qkv + 384 + w * 32 + 16 * mv + 4 * g);
#pragma unroll
            for (int n = 0; n < 4; ++n) vacc[mv][n] = (f4){bv.x, bv.y, bv.z, bv.w};
        }
#pragma unroll
        for (int ks = 0; ks < 6; ++ks) {
            h8 wA0 = *(const h8*)(Wv + (w * 32 + c16) * 192 + 32 * ks + 8 * g);
            h8 wA1 = *(const h8*)(Wv + (w * 32 + 16 + c16) * 192 + 32 * ks + 8 * g);
#pragma unroll
            for (int n = 0; n < 4; ++n) {
                const h8 xv = cvt8(xR[n] + 32 * ks + 8 * g);
                vacc[0][n] = MFMA(wA0, xv, vacc[0][n]);
                vacc[1][n] = MFMA(wA1, xv, vacc[1][n]);
            }
        }
        // rows 0..31 (channels); overwrites K rows 0..31 — kb already in regs
#pragma unroll
        for (int mv = 0; mv < 2; ++mv)
#pragma unroll
            for (int n = 0; n < 4; ++n)
#pragma unroll
                for (int rg = 0; rg < 4; ++rg)
                    bounce[(16 * mv + 4 * g + rg) * 72 + 16 * n + c16] =
                        (_Float16)vacc[mv][n][rg];
    }
    h8 vb[2][2];
#pragma unroll
    for (int ks2 = 0; ks2 < 2; ++ks2)
#pragma unroll
        for (int n = 0; n < 2; ++n)
            vb[ks2][n] = *(const h8*)(bounce + (16 * n + c16) * 72 + 32 * ks2 + 8 * g);

    // ---------------- S = Q@K^T + bias/mask table ----------------
    f4 s[4][4];
    {
        const float* tb = tab + ((ty * 6 + w) << 12);
#pragma unroll
        for (int m = 0; m < 4; ++m)
#pragma unroll
            for (int n = 0; n < 4; ++n)
#pragma unroll
                for (int rg = 0; rg < 4; ++rg)
                    s[m][n][rg] = tb[(16 * m + 4 * g + rg) * 64 + 16 * n + c16];
#pragma unroll
        for (int m = 0; m < 4; ++m)
#pragma unroll
            for (int n = 0; n < 4; ++n)
                s[m][n] = MFMA(qa[m], kb[n], s[m][n]);
    }

    // ---------------- softmax (P unnormalized; inv folded into O) ----------------
    f4 inv4[4];
#pragma unroll
    for (int m = 0; m < 4; ++m) {
#pragma unroll
        for (int rg = 0; rg < 4; ++rg) {
            float mx = fmaxf(fmaxf(s[m][0][rg], s[m][1][rg]),
                             fmaxf(s[m][2][rg], s[m][3][rg]));
            mx = fmaxf(mx, __shfl_xor(mx, 1));
            mx = fmaxf(mx, __shfl_xor(mx, 2));
            mx = fmaxf(mx, __shfl_xor(mx, 4));
            mx = fmaxf(mx, __shfl_xor(mx, 8));
            const float e0 = __expf(s[m][0][rg] - mx);
            const float e1 = __expf(s[m][1][rg] - mx);
            const float e2 = __expf(s[m][2][rg] - mx);
            const float e3 = __expf(s[m][3][rg] - mx);
            float sm = e0 + e1 + e2 + e3;
            sm += __shfl_xor(sm, 1);
            sm += __shfl_xor(sm, 2);
            sm += __shfl_xor(sm, 4);
            sm += __shfl_xor(sm, 8);
            inv4[m][rg] = 1.0f / sm;
            _Float16* prow = bounce + (16 * m + 4 * g + rg) * 72 + c16;
            prow[0]  = (_Float16)e0;
            prow[16] = (_Float16)e1;
            prow[32] = (_Float16)e2;
            prow[48] = (_Float16)e3;
        }
    }

    // ---------------- O = P @ V, scaled by inv ----------------
    f4 o[4][2];
    {
        h8 pa[4][2];
#pragma unroll
        for (int m = 0; m < 4; ++m)
#pragma unroll
            for (int ks2 = 0; ks2 < 2; ++ks2)
                pa[m][ks2] = *(const h8*)(bounce + (16 * m + c16) * 72 + 32 * ks2 + 8 * g);
#pragma unroll
        for (int m = 0; m < 4; ++m)
#pragma unroll
            for (int n = 0; n < 2; ++n) {
                f4 acc = (f4){0.f, 0.f, 0.f, 0.f};
                acc = MFMA(pa[m][0], vb[0][n], acc);
                acc = MFMA(pa[m][1], vb[1][n], acc);
                o[m][n] = acc;
            }
#pragma unroll
        for (int m = 0; m < 4; ++m)
#pragma unroll
            for (int n = 0; n < 2; ++n)
#pragma unroll
                for (int rg = 0; rg < 4; ++rg)
                    o[m][n][rg] *= inv4[m][rg];
    }

    __syncthreads();                           // all bounce use done -> pool becomes sO

    // ---------------- O concat: sO[token][head*32 + ch], pitch 200 ----------------
    {
        _Float16* sO = sPool;
#pragma unroll
        for (int m = 0; m < 4; ++m)
#pragma unroll
            for (int n = 0; n < 2; ++n)
#pragma unroll
                for (int rg = 0; rg < 4; ++rg)
                    sO[(16 * m + 4 * g + rg) * 200 + w * 32 + 16 * n + c16] =
                        (_Float16)o[m][n][rg];
    }
    __syncthreads();

    // ---------------- proj: wave w computes out channels 32w..32w+31 ----------------
    f4 pacc[4][2];
#pragma unroll
    for (int n = 0; n < 2; ++n) {
        const float bo = b_out[32 * w + 16 * n + c16];
#pragma unroll
        for (int m = 0; m < 4; ++m) pacc[m][n] = (f4){bo, bo, bo, bo};
    }
    {
        const _Float16* sO = sPool;
#pragma unroll
        for (int ks = 0; ks < 6; ++ks) {
            h8 wB0 = *(const h8*)(Wo + (32 * w + c16) * 192 + 32 * ks + 8 * g);
            h8 wB1 = *(const h8*)(Wo + (32 * w + 16 + c16) * 192 + 32 * ks + 8 * g);
#pragma unroll
            for (int m = 0; m < 4; ++m) {
                const h8 oa = *(const h8*)(sO + (16 * m + c16) * 200 + 32 * ks + 8 * g);
                pacc[m][0] = MFMA(oa, wB0, pacc[m][0]);
                pacc[m][1] = MFMA(oa, wB1, pacc[m][1]);
            }
        }
    }

    // ---------------- write out (inverse roll folded into scatter) ----------------
#pragma unroll
    for (int m = 0; m < 4; ++m)
#pragma unroll
        for (int rg = 0; rg < 4; ++rg) {
            const int tok = 16 * m + 4 * g + rg;
            const int ho = (whi * 8 + (tok >> 3) + SHIFTV) & 255;
            const int wo = (wwi * 8 + (tok & 7) + SHIFTV) & 255;
            float* po = out + ((bi * IMG + ho) * IMG + wo) * 192 + 32 * w + c16;
            po[0]  = pacc[m][0][rg];
            po[16] = pacc[m][1][rg];
        }
}

extern "C" void kernel_launch(void* const* d_in, const int* in_sizes, int n_in,
                              void* d_out, int out_size, void* d_ws, size_t ws_size,
                              hipStream_t stream)
{
    const float* x       = (const float*)d_in[0];
    const float* b       = (const float*)d_in[1];
    const float* w_qkv   = (const float*)d_in[2];
    const float* b_qkv   = (const float*)d_in[3];
    const float* w_qkv_b = (const float*)d_in[4];
    const float* b_qkv_b = (const float*)d_in[5];
    const float* rel     = (const float*)d_in[6];
    const float* w_out   = (const float*)d_in[7];
    const float* b_out   = (const float*)d_in[8];
    float* out = (float*)d_out;

    _Float16* wh = (_Float16*)d_ws;                      // 4 x 36864 fp16 = 294912 B
    float* tab = (float*)((char*)d_ws + 294912);         // 98304 f32 = 393216 B

    prep_weights<<<576, 256, 0, stream>>>(w_qkv_b, w_qkv, w_out, wh);
    prep_table<<<384, 256, 0, stream>>>(rel, tab);
    wmca_hpw<<<2048, 384, 0, stream>>>(x, b, b_qkv, b_qkv_b, b_out, wh, tab, out);
}